// Round 8
// baseline (156.044 us; speedup 1.0000x reference)
//
#include <hip/hip_runtime.h>
#include <hip/hip_bf16.h>

#define N_CL   50000
#define FEAT   64
#define HID    256
#define KD     256
#define T_SEL  1000
#define NBLK   782                 // ceil(50000/64) clause groups
#define JSPLIT 4                   // hidden-quarter blocks per clause group (R4-proven)

#define NQUAD  12500               // N_CL/4 quads per mask row (exact)
#define NCHUNK 20                  // clause chunks
#define CHUNKQ 625                 // quads per chunk (20*625 = 12500)
#define GEV    5                   // same-parity events per block
#define SLOTS  10                  // ceil(625/64)
#define LASTW  49                  // valid lanes in slot 9 (625 - 9*64)

// ws layout (floats). Event-phase buffers OVERLAY P (dead after logits_fin).
// ctab = uint4[2][NQUAD] = 2*12500*16B = 100000 floats.
#define WK_OFF   0                           // 256*2 folded weights
#define CK_OFF   512                         // 2 bias constants
#define MQ_OFF   514                         // 2 uint max-keys
#define P_OFF    520                         // JSPLIT*2*N_CL partials (400000 f)
#define LG_OFF   (P_OFF + JSPLIT * 2 * N_CL) // 2*N_CL final logits f32 (100000 f)
#define CTAB_OFF 520                         // packed (l,e) table (100000 f)
#define ACC_OFF  (CTAB_OFF + 100000)         // float4[T_SEL][NCHUNK] (80000 f)
// overlay ends at 180520 << LG_OFF (400520); lg untouched.

__device__ __forceinline__ unsigned fkey(float f) {
    unsigned u = __float_as_uint(f);
    return (u & 0x80000000u) ? ~u : (u | 0x80000000u);   // monotone float->uint
}
__device__ __forceinline__ float finv(unsigned k) {
    unsigned u = (k & 0x80000000u) ? (k ^ 0x80000000u) : ~k;
    return __uint_as_float(u);
}
__device__ __forceinline__ unsigned short f2bf(float f) {   // RNE bf16 pack
    unsigned u = __float_as_uint(f);
    return (unsigned short)((u + 0x7FFFu + ((u >> 16) & 1u)) >> 16);
}
__device__ __forceinline__ float eLO(unsigned u) {          // exp part (low16)
    return __uint_as_float(u << 16);
}
__device__ __forceinline__ float lHI(unsigned u) {          // logit part (high16)
    return __uint_as_float(u & 0xFFFF0000u);
}

// ---------------------------------------------------------------- kernel A
__global__ __launch_bounds__(256) void prep_kernel(
        const float* __restrict__ W2, const float* __restrict__ b2,
        const float* __restrict__ keysW,
        float* __restrict__ wk, float* __restrict__ ck,
        unsigned* __restrict__ mq) {
    __shared__ float sk0[KD], sk1[KD], sb2[KD], red[256];
    int tid = threadIdx.x;
    sk0[tid] = keysW[tid];
    sk1[tid] = keysW[KD + tid];
    sb2[tid] = b2[tid];
    if (tid < 2) mq[tid] = 0u;
    __syncthreads();

    const float* w2r = W2 + (size_t)tid * KD;
    float a0 = 0.f, a1 = 0.f;
    #pragma unroll 4
    for (int k = 0; k < KD; k++) {
        float w = w2r[k];
        a0 = fmaf(w, sk0[k], a0);
        a1 = fmaf(w, sk1[k], a1);
    }
    wk[tid * 2 + 0] = a0;
    wk[tid * 2 + 1] = a1;

    red[tid] = sk0[tid] * sb2[tid];
    __syncthreads();
    for (int s = 128; s > 0; s >>= 1) { if (tid < s) red[tid] += red[tid + s]; __syncthreads(); }
    if (tid == 0) ck[0] = red[0];
    __syncthreads();
    red[tid] = sk1[tid] * sb2[tid];
    __syncthreads();
    for (int s = 128; s > 0; s >>= 1) { if (tid < s) red[tid] += red[tid + s]; __syncthreads(); }
    if (tid == 0) ck[1] = red[0];
}

// ---------------------------------------------------------------- kernel B
// MLP partial logits (R4-proven). k-loop FULLY unrolled -> x[] in VGPRs.
__global__ __launch_bounds__(64, 2) void mlp_kernel(
        const float* __restrict__ X, const float* __restrict__ W1,
        const float* __restrict__ b1, const float* __restrict__ wk,
        float* __restrict__ P) {
    int nb = blockIdx.x >> 2;       // p adjacent: 4 blocks sharing X rows
    int p  = blockIdx.x & 3;
    int n  = nb * 64 + threadIdx.x;
    int nc = (n < N_CL) ? n : (N_CL - 1);

    float x[FEAT];
    const float4* xp = (const float4*)(X + (size_t)nc * FEAT);
    #pragma unroll
    for (int k4 = 0; k4 < FEAT / 4; k4++) {
        float4 v = xp[k4];
        x[4 * k4 + 0] = v.x; x[4 * k4 + 1] = v.y;
        x[4 * k4 + 2] = v.z; x[4 * k4 + 3] = v.w;
    }

    float l0 = 0.f, l1 = 0.f;
    int j0 = p * 64;
    for (int jg = 0; jg < 64; jg += 16) {   // runtime loop: h indexed by u only
        float h[16];
        #pragma unroll
        for (int u = 0; u < 16; u++) h[u] = b1[j0 + jg + u];
        #pragma unroll
        for (int k = 0; k < FEAT; k++) {    // FULL unroll: x[k] static
            const float* w1r = W1 + (size_t)k * HID + j0 + jg;
            float xv = x[k];
            #pragma unroll
            for (int u = 0; u < 16; u++) h[u] = fmaf(xv, w1r[u], h[u]);
        }
        #pragma unroll
        for (int u = 0; u < 16; u++) {
            float hv = fmaxf(h[u], 0.0f);
            l0 = fmaf(hv, wk[(j0 + jg + u) * 2 + 0], l0);
            l1 = fmaf(hv, wk[(j0 + jg + u) * 2 + 1], l1);
        }
    }
    if (n < N_CL) {
        P[((size_t)p * 2 + 0) * N_CL + n] = l0;
        P[((size_t)p * 2 + 1) * N_CL + n] = l1;
    }
}

// ---------------------------------------------------------------- kernel C
__global__ __launch_bounds__(256) void logits_fin(
        const float* __restrict__ P, const float* __restrict__ ck,
        float* __restrict__ lg, unsigned* __restrict__ mq) {
    int n = blockIdx.x * 256 + threadIdx.x;
    float m0 = -1e30f, m1 = -1e30f;
    if (n < N_CL) {
        float l0 = ck[0], l1 = ck[1];
        #pragma unroll
        for (int p = 0; p < JSPLIT; p++) {
            l0 += P[((size_t)p * 2 + 0) * N_CL + n];
            l1 += P[((size_t)p * 2 + 1) * N_CL + n];
        }
        lg[n]        = l0;
        lg[N_CL + n] = l1;
        m0 = l0; m1 = l1;
    }
    for (int off = 32; off; off >>= 1) {
        m0 = fmaxf(m0, __shfl_xor(m0, off));
        m1 = fmaxf(m1, __shfl_xor(m1, off));
    }
    __shared__ float sm0[4], sm1[4];
    int w = threadIdx.x >> 6;
    if ((threadIdx.x & 63) == 0) { sm0[w] = m0; sm1[w] = m1; }
    __syncthreads();
    if (threadIdx.x == 0) {
        m0 = fmaxf(fmaxf(sm0[0], sm0[1]), fmaxf(sm0[2], sm0[3]));
        m1 = fmaxf(fmaxf(sm1[0], sm1[1]), fmaxf(sm1[2], sm1[3]));
        atomicMax(mq + 0, fkey(m0));
        atomicMax(mq + 1, fkey(m1));
    }
}

// ---------------------------------------------------------------- kernel C2
// Pack (l, e=exp(l-M)) as bf16 pairs in one uint per clause. 400KB total.
__global__ __launch_bounds__(256) void epack_kernel(
        const float* __restrict__ lg, const unsigned* __restrict__ mq,
        uint4* __restrict__ ctab) {
    int quad = blockIdx.x * 256 + threadIdx.x;
    if (quad >= NQUAD) return;
    #pragma unroll
    for (int q = 0; q < 2; q++) {
        float4 f = ((const float4*)lg)[(size_t)q * NQUAD + quad];
        float M = finv(mq[q]);
        uint4 cv;
        cv.x = ((unsigned)f2bf(f.x) << 16) | f2bf(__expf(f.x - M));
        cv.y = ((unsigned)f2bf(f.y) << 16) | f2bf(__expf(f.y - M));
        cv.z = ((unsigned)f2bf(f.z) << 16) | f2bf(__expf(f.z - M));
        cv.w = ((unsigned)f2bf(f.w) << 16) | f2bf(__expf(f.w - M));
        ctab[(size_t)q * NQUAD + quad] = cv;
    }
}

// ---------------------------------------------------------------- kernel D
// Block = single wave, (clause chunk c, 5 same-parity events). Table slice
// (10KB) in LDS; per event all 20 mask loads (10 pass + 10 good int4) issue
// as one independent batch -> deep MLP; wave-local shfl reduce; one float4
// store per (event, chunk). No syncthreads in the hot loop, no atomics.
__global__ __launch_bounds__(64) void emain_kernel(
        const int* __restrict__ pass, const int* __restrict__ good,
        const int* __restrict__ qidx, const uint4* __restrict__ ctab,
        float4* __restrict__ acc) {
    int bid  = blockIdx.x;
    int c    = bid % NCHUNK;
    int rest = bid / NCHUNK;       // [0, 200)
    int par  = rest & 1;
    int grp  = rest >> 1;          // [0, 100)
    int lane = threadIdx.x;

    int t0 = par + 2 * (grp * GEV);
    int q  = qidx[t0] & 1;         // uniform across the group (same parity)

    __shared__ uint4 ct[CHUNKQ];   // 10 KB
    for (int i = lane; i < CHUNKQ; i += 64)
        ct[i] = ctab[(size_t)q * NQUAD + c * CHUNKQ + i];
    __syncthreads();

    int idx[SLOTS];
    #pragma unroll
    for (int s = 0; s < SLOTS; s++) {
        int i = s * 64 + lane;
        idx[s] = (i < CHUNKQ) ? i : (CHUNKQ - 1);   // clamp (slot 9 tail)
    }
    bool lastok = lane < LASTW;

    #pragma unroll
    for (int e = 0; e < GEV; e++) {
        int t = t0 + 2 * e;
        const int4* pb = (const int4*)pass + (size_t)t * NQUAD + c * CHUNKQ;
        const int4* gb = (const int4*)good + (size_t)t * NQUAD + c * CHUNKQ;

        int4 pm[SLOTS], gm[SLOTS];
        #pragma unroll
        for (int s = 0; s < SLOTS; s++) pm[s] = pb[idx[s]];
        #pragma unroll
        for (int s = 0; s < SLOTS; s++) gm[s] = gb[idx[s]];

        float sa = 0.f, sga = 0.f;
        int np = 0, ng = 0;
        #pragma unroll
        for (int s = 0; s < SLOTS; s++) {
            uint4 cv = ct[idx[s]];
            int4 p = pm[s], g = gm[s];
            if (s == SLOTS - 1 && !lastok) {        // zero clamped lanes
                p = make_int4(0, 0, 0, 0);
                g = make_int4(0, 0, 0, 0);
            }
            np += p.x + p.y + p.z + p.w;
            ng += g.x + g.y + g.z + g.w;
            sa  += p.x ? eLO(cv.x) : 0.0f;
            sa  += p.y ? eLO(cv.y) : 0.0f;
            sa  += p.z ? eLO(cv.z) : 0.0f;
            sa  += p.w ? eLO(cv.w) : 0.0f;
            sga += g.x ? lHI(cv.x) : 0.0f;
            sga += g.y ? lHI(cv.y) : 0.0f;
            sga += g.z ? lHI(cv.z) : 0.0f;
            sga += g.w ? lHI(cv.w) : 0.0f;
        }
        for (int off = 32; off; off >>= 1) {
            sa  += __shfl_xor(sa, off);
            sga += __shfl_xor(sga, off);
            np  += __shfl_xor(np, off);
            ng  += __shfl_xor(ng, off);
        }
        if (lane == 0)
            acc[(size_t)t * NCHUNK + c] =
                make_float4(sa, sga, (float)np, (float)ng);
    }
}

// ---------------------------------------------------------------- kernel E
__global__ __launch_bounds__(1024) void final_kernel(
        const int* __restrict__ qidx, const float4* __restrict__ acc,
        const unsigned* __restrict__ mq, float* __restrict__ out) {
    int t = threadIdx.x;
    float s = 0.f, sg = 0.f, np = 0.f, ng = 0.f;
    int q = 0;
    if (t < T_SEL) {
        #pragma unroll 4
        for (int c = 0; c < NCHUNK; c++) {
            float4 a = acc[(size_t)t * NCHUNK + c];
            s += a.x; sg += a.y; np += a.z; ng += a.w;
        }
        q = qidx[t] & 1;
    }
    float M  = finv(mq[q]);
    float nb = np - ng;
    int valid = (t < T_SEL) && (ng > 0.5f) && (nb > 0.5f);

    __shared__ int sc[1024];
    sc[t] = valid;
    __syncthreads();
    for (int off = 1; off < 1024; off <<= 1) {
        int v = (t >= off) ? sc[t - off] : 0;
        __syncthreads();
        sc[t] += v;
        __syncthreads();
    }
    int sb    = sc[t] - valid;          // exclusive scan
    int steps = sc[1023];               // total valid count

    float ce   = logf(s) + M - sg / fmaxf(ng, 1.0f);
    float wgt  = powf(0.995f, (float)sb) * nb / fmaxf(np, 1.0f);
    float term = valid ? wgt * ce : 0.0f;

    __shared__ float sf[1024];
    sf[t] = term;
    __syncthreads();
    for (int off = 512; off; off >>= 1) {
        if (t < off) sf[t] += sf[t + off];
        __syncthreads();
    }
    if (t == 0) out[0] = sf[0] / fmaxf((float)steps, 1.0f);
}

extern "C" void kernel_launch(void* const* d_in, const int* in_sizes, int n_in,
                              void* d_out, int out_size, void* d_ws, size_t ws_size,
                              hipStream_t stream) {
    const float* X     = (const float*)d_in[0];
    const float* W1    = (const float*)d_in[1];
    const float* b1    = (const float*)d_in[2];
    const float* W2    = (const float*)d_in[3];
    const float* b2    = (const float*)d_in[4];
    const float* keysW = (const float*)d_in[5];
    const int*   pass  = (const int*)d_in[6];   // bool -> int32, one per clause
    const int*   good  = (const int*)d_in[7];
    const int*   qidx  = (const int*)d_in[8];

    float*    ws   = (float*)d_ws;
    float*    wk   = ws + WK_OFF;
    float*    ck   = ws + CK_OFF;
    unsigned* mq   = (unsigned*)(ws + MQ_OFF);
    float*    P    = ws + P_OFF;
    float*    lg   = ws + LG_OFF;
    uint4*    ctab = (uint4*)(ws + CTAB_OFF);    // overlays P (dead)
    float4*   acc  = (float4*)(ws + ACC_OFF);    // overlays P (dead)
    float*    out  = (float*)d_out;

    hipLaunchKernelGGL(prep_kernel, dim3(1), dim3(256), 0, stream,
                       W2, b2, keysW, wk, ck, mq);
    hipLaunchKernelGGL(mlp_kernel, dim3(NBLK * JSPLIT), dim3(64), 0, stream,
                       X, W1, b1, wk, P);
    hipLaunchKernelGGL(logits_fin, dim3((N_CL + 255) / 256), dim3(256), 0, stream,
                       P, ck, lg, mq);
    hipLaunchKernelGGL(epack_kernel, dim3((NQUAD + 255) / 256), dim3(256), 0, stream,
                       lg, mq, ctab);
    hipLaunchKernelGGL(emain_kernel, dim3(NCHUNK * 200), dim3(64), 0, stream,
                       pass, good, qidx, ctab, acc);
    hipLaunchKernelGGL(final_kernel, dim3(1), dim3(1024), 0, stream,
                       qidx, acc, mq, out);
}